// Round 9
// baseline (145.345 us; speedup 1.0000x reference)
//
#include <hip/hip_runtime.h>
#include <hip/hip_bf16.h>

typedef __attribute__((ext_vector_type(8))) short bf16x8;
typedef __attribute__((ext_vector_type(4))) float f32x4;
typedef __attribute__((ext_vector_type(2))) unsigned int u32x2;
typedef unsigned short u16;

#define B_  2
#define T_  2048
#define C_  1024
#define H_  16
#define HD_ 64

static __device__ __forceinline__ u16 f2bf(float f) {
  unsigned u = __float_as_uint(f);
  u += 0x7fffu + ((u >> 16) & 1u);   // round-to-nearest-even
  return (u16)(u >> 16);
}

// ---------------------------------------------------------------------------
// Kernel 0 "prep": two regions in one dispatch
//   [0,1024):   pack block (bh,kt): read 64x64 X tile fp32 once ->
//               Xb (bf16 row-major), Vf (MFMA-fragment layout), and
//               SubP64[bh][kt][d] = column sums (fp32, via xor-shuffles)
//   [1024,3072): convert W fp32->bf16 (float4 vectorized)
// ---------------------------------------------------------------------------
#define NW4 524288    // W float4 count
__global__ __launch_bounds__(256) void prep(
    const float* __restrict__ X, const float* __restrict__ W,
    u16* __restrict__ Xb, u16* __restrict__ Wb,
    u16* __restrict__ Vf, float* __restrict__ SubP64)
{
  __shared__ u16 tr[64][65];
  __shared__ float cs[4][64];
  const int blk = blockIdx.x;
  const int tid = threadIdx.x;

  if (blk < 1024) {                       // ---- pack + convert-X + colsums ----
    const int kt = blk & 31, bh = blk >> 5;
    const int b = bh >> 4, h = bh & 15;
    const int w = tid >> 6, lane = tid & 63;
    {
      const int row = tid >> 2;            // 0..63
      const int c0  = (tid & 3) * 16;      // float col base
      const float* xp = X + ((size_t)b * T_ + kt * 64 + row) * C_ + h * 64 + c0;
      float vals[16];
#pragma unroll
      for (int q = 0; q < 4; ++q) {
        float4 v = *(const float4*)(xp + q * 4);
        vals[q * 4 + 0] = v.x; vals[q * 4 + 1] = v.y;
        vals[q * 4 + 2] = v.z; vals[q * 4 + 3] = v.w;
      }
      u16 xb[16];
#pragma unroll
      for (int i = 0; i < 16; ++i) xb[i] = f2bf(vals[i]);
      u16* xq = Xb + ((size_t)(b * T_ + kt * 64 + row)) * C_ + h * 64 + c0;
      *(bf16x8*)xq       = *(const bf16x8*)&xb[0];
      *(bf16x8*)(xq + 8) = *(const bf16x8*)&xb[8];
#pragma unroll
      for (int i = 0; i < 16; ++i) tr[row][c0 + i] = xb[i];
#pragma unroll
      for (int m = 4; m <= 32; m <<= 1)
#pragma unroll
        for (int i = 0; i < 16; ++i) vals[i] += __shfl_xor(vals[i], m);
      if (lane < 4) {
        float* dst = &cs[w][lane * 16];
#pragma unroll
        for (int q = 0; q < 4; ++q) {
          f32x4 s4 = { vals[q * 4 + 0], vals[q * 4 + 1], vals[q * 4 + 2], vals[q * 4 + 3] };
          *(f32x4*)&dst[q * 4] = s4;
        }
      }
    }
    __syncthreads();
    {
      const int quad = (lane >> 4), l16 = lane & 15;
      u16* outb = Vf + ((size_t)bh * 32 + kt) * 4096;
#pragma unroll
      for (int c = 0; c < 2; ++c) {
        u16 tmp[8];
#pragma unroll
        for (int j = 0; j < 8; ++j) tmp[j] = tr[c * 32 + quad * 8 + j][w * 16 + l16];
        *(bf16x8*)&outb[((w * 2 + c) * 64 + lane) * 8] = *(const bf16x8*)tmp;
      }
    }
    if (tid < 64)
      SubP64[(size_t)bh * 2048 + kt * 64 + tid] =
          cs[0][tid] + cs[1][tid] + cs[2][tid] + cs[3][tid];
  } else {                                // ---- convert W ----
    int i = (blk - 1024) * 256 + tid;
    float4 v = ((const float4*)W)[i];
    ushort4 u = { f2bf(v.x), f2bf(v.y), f2bf(v.z), f2bf(v.w) };
    ((ushort4*)Wb)[i] = u;
  }
}

// ---------------------------------------------------------------------------
// Kernel 1: qk = Xb @ Wb^T  (M=4096,N=2048,K=1024).
// ROUND-9: tile 128x64 (was 128x128), grid 32x32 = 1024 blocks.
// Rationale: r8's counted-vmcnt raced (tripwire, reverted; this family gets
// NO raw-barrier protocols). m102 shape data: same 2-barrier structure is
// 874TF at 4 blocks/CU vs 320TF at 1; our 512-block grid = 2/CU (LDS 64KB
// also capped 2). 128x64 tile -> LDS 48KB -> 3 blocks/CU, 12 waves/CU,
// acc halves to 32 VGPR. Cross-block overlap now covers the barrier drain.
// Keeps: __syncthreads dbuf (tripwire-proven), r7 T2 XOR-swizzle both sides
// (algebra: LDS(row,ch)=G(ch^row&7); read XORs back -> bit-identical data).
// Q row-major [B,H,T,hd] PRE-SCALED by 0.125; K into fragment-linear Kf.
// ---------------------------------------------------------------------------
__global__ __launch_bounds__(256) void gemm_qk(
    const u16* __restrict__ Xb, const u16* __restrict__ Wb,
    u16* __restrict__ Qo, u16* __restrict__ Kf)
{
  __shared__ __align__(16) u16 As[2][128 * 64];   // 32KB
  __shared__ __align__(16) u16 Bs[2][64 * 64];    // 16KB

  const int tid  = threadIdx.x;
  const int w    = tid >> 6;
  const int lane = tid & 63;
  const int quad = lane >> 4;
  const int l16  = lane & 15;
  const int m0 = blockIdx.y * 128;
  const int n0 = blockIdx.x * 64;

  const int grow = w * 8 + ((lane >> 3) & 7);
  // source-side swizzle: global chunk = (dest chunk) ^ (row&7)
  const int gcol = (((lane & 7) ^ ((lane >> 3) & 7)) * 8);

  f32x4 zero = {0.f, 0.f, 0.f, 0.f};
  f32x4 acc[4][2];
#pragma unroll
  for (int i = 0; i < 4; ++i)
#pragma unroll
    for (int j = 0; j < 2; ++j) acc[i][j] = zero;

  const int wr = (w >> 1) * 64, wc = (w & 1) * 32;

  const u16* gax = Xb + (size_t)(m0 + grow) * C_ + gcol;
  const u16* gbx = Wb + (size_t)(n0 + grow) * C_ + gcol;

#define GISSUE(K, BUF)                                                      \
  {                                                                         \
    _Pragma("unroll") for (int r = 0; r < 4; ++r) {                         \
      __builtin_amdgcn_global_load_lds(                                     \
          (const __attribute__((address_space(1))) void*)(gax + (size_t)r * 32 * C_ + (K)), \
          (__attribute__((address_space(3))) void*)&As[BUF][(w * 8 + r * 32) * 64], \
          16, 0, 0);                                                        \
    }                                                                       \
    _Pragma("unroll") for (int r = 0; r < 2; ++r) {                         \
      __builtin_amdgcn_global_load_lds(                                     \
          (const __attribute__((address_space(1))) void*)(gbx + (size_t)r * 32 * C_ + (K)), \
          (__attribute__((address_space(3))) void*)&Bs[BUF][(w * 8 + r * 32) * 64], \
          16, 0, 0);                                                        \
    }                                                                       \
  }

  GISSUE(0, 0);
#pragma unroll 2
  for (int it = 0; it < 16; ++it) {
    const int cur = it & 1;
    __syncthreads();                 // publishes buf[cur]; buf[cur^1] free
    if (it < 15) GISSUE((it + 1) * 64, cur ^ 1);
#pragma unroll
    for (int c = 0; c < 2; ++c) {
      bf16x8 af[4], bf[2];
#pragma unroll
      for (int i = 0; i < 4; ++i)
        af[i] = *(const bf16x8*)&As[cur][(wr + i * 16 + l16) * 64
                                         + (((c * 4 + quad) ^ (l16 & 7)) * 8)];
#pragma unroll
      for (int j = 0; j < 2; ++j)
        bf[j] = *(const bf16x8*)&Bs[cur][(wc + j * 16 + l16) * 64
                                         + (((c * 4 + quad) ^ (l16 & 7)) * 8)];
#pragma unroll
      for (int i = 0; i < 4; ++i)
#pragma unroll
        for (int j = 0; j < 2; ++j)
          acc[i][j] = __builtin_amdgcn_mfma_f32_16x16x32_bf16(af[i], bf[j], acc[i][j], 0, 0, 0);
    }
  }
#undef GISSUE

  // C/D layout: col = lane&15, row = quad*4 + reg (verified m89/m91)
#pragma unroll
  for (int i = 0; i < 4; ++i) {
    const int t_base = m0 + wr + i * 16;       // 16-aligned; wr multiple of 64
    const int bidx = t_base >> 11;
    const int kt   = (t_base & 2047) >> 6;
    const int trow = (t_base & 2047) + quad * 4;
#pragma unroll
    for (int j = 0; j < 2; ++j) {
      const int n = n0 + wc + j * 16 + l16;    // wave-uniform branch base
      if (n < C_) {
        const int hq = n >> 6, d = n & 63;
        u16* qp = Qo + (((size_t)bidx * H_ + hq) * T_ + trow) * HD_ + d;
#pragma unroll
        for (int r = 0; r < 4; ++r) qp[(size_t)r * HD_] = f2bf(0.125f * acc[i][j][r]);
      } else {
        const int nh = n - C_;
        const int hh = nh >> 6, d = nh & 63;
        u16* kp = Kf + (((((size_t)(bidx * H_ + hh) * 32 + kt) * 4 + i) * 2 + (d >> 5)) * 64
                        + ((d >> 3) & 3) * 16 + quad * 4) * 8 + (d & 7);
#pragma unroll
        for (int r = 0; r < 4; ++r) kp[(size_t)r * 8] = f2bf(acc[i][j][r]);
      }
    }
  }
}

// ---------------------------------------------------------------------------
// Kernel 2 (unchanged from round 6/7, passing + tripwire-clean):
// LDS-staged flash attention, P fully in-register via swapped QK^T +
// cvt_pk_bf16 + permlane32/16_swap builtins; parity split over kt across
// wave halves with additive LDS combine; fused epilogue.
// ---------------------------------------------------------------------------
__global__ __launch_bounds__(512) void attn_kernel(
    const u16* __restrict__ Q, const u16* __restrict__ Kf, const u16* __restrict__ Vf,
    const float* __restrict__ SubP64, const float* __restrict__ X, float* __restrict__ out,
    const float* __restrict__ alphap, const float* __restrict__ betap,
    const float* __restrict__ gammap)
{
  __shared__ __align__(16) char smem[32768];
  u16 (*Ks)[4096] = (u16(*)[4096])(smem);            // [2][4096] u16 = 16KB
  u16 (*Vs)[4096] = (u16(*)[4096])(smem + 16384);    // [2][4096] u16 = 16KB

  const int tid  = threadIdx.x;
  const int w    = tid >> 6;          // 0..7
  const int wq   = w & 3;             // q-row group (16 rows)
  const int parity = w >> 2;          // kt parity
  const int lane = tid & 63;
  const int quad = lane >> 4;
  const int l16  = lane & 15;
  const int qt = 31 - blockIdx.y;     // LPT: heavy q-tiles first
  const int bh = blockIdx.x;
  const int b = bh >> 4, h = bh & 15;

  const u16* kfb = Kf + (size_t)bh * T_ * HD_;
  const u16* vfb = Vf + (size_t)bh * T_ * HD_;

  bf16x8 qfrag[2];
  {
    const u16* qp = Q + ((size_t)bh * T_ + qt * 64 + wq * 16 + l16) * HD_ + quad * 8;
    qfrag[0] = *(const bf16x8*)qp;
    qfrag[1] = *(const bf16x8*)(qp + 32);
  }

  bf16x8 onesf;
#pragma unroll
  for (int j = 0; j < 8; ++j) onesf[j] = (short)0x3F80;

  f32x4 zero = {0.f, 0.f, 0.f, 0.f};
  f32x4 acc[4] = {zero, zero, zero, zero};
  f32x4 accl = zero;

  // Stage one (K,V) tile pair: 16 chunks of 1KB; waves 0-3 -> K, 4-7 -> V,
  // 2 chunks each. LDS dst wave-uniform; src carries lane*16B.
#define STAGE(KT, BUF)                                                        \
  {                                                                           \
    const u16* sb = (w < 4) ? kfb : vfb;                                      \
    u16* db = (w < 4) ? &Ks[BUF][0] : &Vs[BUF][0];                            \
    const int ch = (w & 3) * 2;                                               \
    _Pragma("unroll") for (int ci = 0; ci < 2; ++ci) {                        \
      __builtin_amdgcn_global_load_lds(                                       \
          (const __attribute__((address_space(1))) void*)(                    \
              sb + (size_t)(KT) * 4096 + (ch + ci) * 512 + lane * 8),         \
          (__attribute__((address_space(3))) void*)(db + (ch + ci) * 512),    \
          16, 0, 0);                                                          \
    }                                                                         \
  }

  STAGE(0, 0);
  for (int kt = 0; kt <= qt; ++kt) {
    const int cur = kt & 1;
    __syncthreads();                 // publishes buf[cur]; buf[cur^1] free
    if (kt < qt) STAGE(kt + 1, cur ^ 1);
    if (cur != parity) continue;     // wave-uniform
    const u16* Ksb = Ks[cur];
    const u16* Vsb = Vs[cur];
    const bool diag = (kt == qt);

    // swapped QK^T: lane(quad,l16) gets S^T[k = nb*16+quad*4+r][q = l16]
    f32x4 sfr[4] = {zero, zero, zero, zero};
#pragma unroll
    for (int cc = 0; cc < 2; ++cc)
#pragma unroll
      for (int nb = 0; nb < 4; ++nb) {
        bf16x8 kf = *(const bf16x8*)&Ksb[((nb * 2 + cc) * 64 + lane) * 8];
        sfr[nb] = __builtin_amdgcn_mfma_f32_16x16x32_bf16(kf, qfrag[cc], sfr[nb], 0, 0, 0);
      }

    // exp + causal mask + pack to bf16 pairs (k ascending within each u32)
    unsigned pkk[4][2];
#pragma unroll
    for (int nb = 0; nb < 4; ++nb) {
      float p[4];
#pragma unroll
      for (int r = 0; r < 4; ++r) {
        float e = __expf(sfr[nb][r]);
        if (diag && (nb * 16 + quad * 4 + r > wq * 16 + l16)) e = 0.f;
        p[r] = e;
      }
      asm("v_cvt_pk_bf16_f32 %0, %1, %2" : "=v"(pkk[nb][0]) : "v"(p[0]), "v"(p[1]));
      asm("v_cvt_pk_bf16_f32 %0, %1, %2" : "=v"(pkk[nb][1]) : "v"(p[2]), "v"(p[3]));
    }

    // redistribute to PV A-fragments via gfx950 builtins (returns
    // {new_vdst, new_vsrc}); routing element-verified:
    //   t[0] = A-frag u32 for even-source-quad pairs, t[1] = odd
#pragma unroll
    for (int g = 0; g < 2; ++g) {
      u32x2 s0 = __builtin_amdgcn_permlane32_swap(pkk[2 * g][0], pkk[2 * g + 1][0], false, false);
      u32x2 s1 = __builtin_amdgcn_permlane32_swap(pkk[2 * g][1], pkk[2 * g + 1][1], false, false);
      u32x2 t0 = __builtin_amdgcn_permlane16_swap(s0[0], s0[1], false, false);
      u32x2 t1 = __builtin_amdgcn_permlane16_swap(s1[0], s1[1], false, false);
      union { unsigned u[4]; bf16x8 v; } pa;
      pa.u[0] = t0[0]; pa.u[1] = t1[0]; pa.u[2] = t0[1]; pa.u[3] = t1[1];
      accl = __builtin_amdgcn_mfma_f32_16x16x32_bf16(pa.v, onesf, accl, 0, 0, 0);
#pragma unroll
      for (int nb = 0; nb < 4; ++nb) {
        bf16x8 vf = *(const bf16x8*)&Vsb[((nb * 2 + g) * 64 + lane) * 8];
        acc[nb] = __builtin_amdgcn_mfma_f32_16x16x32_bf16(pa.v, vf, acc[nb], 0, 0, 0);
      }
    }
  }
#undef STAGE

  // ---------------- combine odd-parity partials into waves 0-3 -------------
  __syncthreads();                        // all waves done with Ks/Vs
  {
    float* comb = (float*)smem;           // 256 x 20 f32 = 20480B
    if (parity == 1) {
      float* dst = comb + ((size_t)(wq * 64 + lane)) * 20;
#pragma unroll
      for (int nb = 0; nb < 4; ++nb) *(f32x4*)&dst[nb * 4] = acc[nb];
      *(f32x4*)&dst[16] = accl;
    }
    __syncthreads();
    if (parity == 0) {
      const float* src = comb + ((size_t)(wq * 64 + lane)) * 20;
#pragma unroll
      for (int nb = 0; nb < 4; ++nb) {
        f32x4 t = *(const f32x4*)&src[nb * 4];
        acc[nb] += t;
      }
      accl += *(const f32x4*)&src[16];
    }
  }
  __syncthreads();                        // comb region about to be reused

  // ---------------- fused epilogue (64 rows, 512 threads) ----------------
  float* Xt = (float*)smem;               // [64][68] f32 = 17408
  float* G  = (float*)(smem + 17408);     // [8][64]
  float* GP = (float*)(smem + 19456);     // [8][64]

  {
    const int row = tid >> 3, c0 = (tid & 7) * 8;
    const float* xp = X + ((size_t)b * T_ + qt * 64 + row) * C_ + h * 64 + c0;
#pragma unroll
    for (int q = 0; q < 2; ++q) {
      float4 v = *(const float4*)(xp + q * 4);
      Xt[row * 68 + c0 + q * 4 + 0] = v.x;
      Xt[row * 68 + c0 + q * 4 + 1] = v.y;
      Xt[row * 68 + c0 + q * 4 + 2] = v.z;
      Xt[row * 68 + c0 + q * 4 + 3] = v.w;
    }
  }
  {
    float p = 0.f;
    for (int i = w; i < qt; i += 8)
      p += SubP64[(size_t)bh * 2048 + i * 64 + lane];
    GP[w * 64 + lane] = p;
  }
  __syncthreads();
  {
    float g = 0.f;
#pragma unroll
    for (int i = 0; i < 8; ++i) g += Xt[(w * 8 + i) * 68 + lane];
    G[w * 64 + lane] = g;
  }
  __syncthreads();
  {
    const float alpha = *alphap, gamma = *gammap;
    float run = 0.f;
#pragma unroll
    for (int k = 0; k < 8; ++k) run += GP[k * 64 + lane];
    for (int g = 0; g < w; ++g) run += G[g * 64 + lane];
    const int tbase = qt * 64 + w * 8;
#pragma unroll
    for (int i = 0; i < 8; ++i) {
      float v = Xt[(w * 8 + i) * 68 + lane];
      run += v;
      Xt[(w * 8 + i) * 68 + lane] =
          alpha * v - gamma * run * __builtin_amdgcn_rcpf((float)(tbase + i + 1));
    }
  }
  __syncthreads();

  if (parity == 0) {
    const float beta = *betap;
    float rl[4];
#pragma unroll
    for (int r = 0; r < 4; ++r) rl[r] = beta * __builtin_amdgcn_rcpf(accl[r]);
    const int myrow = wq * 16 + quad * 4;
#pragma unroll
    for (int nb = 0; nb < 4; ++nb) {
#pragma unroll
      for (int r = 0; r < 4; ++r) {
        int t = qt * 64 + myrow + r;
        int d = nb * 16 + l16;
        out[((size_t)b * T_ + t) * C_ + h * 64 + d] =
            Xt[(myrow + r) * 68 + d] + rl[r] * acc[nb][r];
      }
    }
  }
}

// ---------------------------------------------------------------------------
extern "C" void kernel_launch(void* const* d_in, const int* in_sizes, int n_in,
                              void* d_out, int out_size, void* d_ws, size_t ws_size,
                              hipStream_t stream) {
  const float* x      = (const float*)d_in[0];
  const float* W_attn = (const float*)d_in[1];
  const float* alphap = (const float*)d_in[2];
  const float* betap  = (const float*)d_in[3];
  const float* gammap = (const float*)d_in[4];
  float* out = (float*)d_out;

  // ws: Qb@0(8M) Kf@8(8M) Vf@16(8M) SubP64@24(.25M) Xb@25(8M) Wb@33(4M) = 37M
  char* ws = (char*)d_ws;
  u16*   Qb     = (u16*)(ws);
  u16*   Kfb    = (u16*)(ws + (8ull  << 20));
  u16*   Vfb    = (u16*)(ws + (16ull << 20));
  float* SubP64 = (float*)(ws + (24ull << 20));
  u16*   Xb     = (u16*)(ws + (25ull << 20));
  u16*   Wb     = (u16*)(ws + (33ull << 20));

  prep<<<3072, 256, 0, stream>>>(x, W_attn, Xb, Wb, Vfb, SubP64);
  gemm_qk<<<dim3(32, 32), 256, 0, stream>>>(Xb, Wb, Qb, Kfb);
  attn_kernel<<<dim3(32, 32), 512, 0, stream>>>(Qb, Kfb, Vfb, SubP64, x, out,
                                                alphap, betap, gammap);
}

// Round 10
// 143.702 us; speedup vs baseline: 1.0114x; 1.0114x over previous
//
#include <hip/hip_runtime.h>
#include <hip/hip_bf16.h>

typedef __attribute__((ext_vector_type(8))) short bf16x8;
typedef __attribute__((ext_vector_type(4))) float f32x4;
typedef __attribute__((ext_vector_type(2))) unsigned int u32x2;
typedef unsigned short u16;

#define B_  2
#define T_  2048
#define C_  1024
#define H_  16
#define HD_ 64

static __device__ __forceinline__ u16 f2bf(float f) {
  unsigned u = __float_as_uint(f);
  u += 0x7fffu + ((u >> 16) & 1u);   // round-to-nearest-even
  return (u16)(u >> 16);
}

// ---------------------------------------------------------------------------
// Kernel 0 "prep": two regions in one dispatch
//   [0,1024):   pack block (bh,kt): read 64x64 X tile fp32 once ->
//               Xb (bf16 row-major), Vf (MFMA-fragment layout), and
//               SubP64[bh][kt][d] = column sums (fp32, via xor-shuffles)
//   [1024,3072): convert W fp32->bf16 (float4 vectorized)
// ---------------------------------------------------------------------------
#define NW4 524288    // W float4 count
__global__ __launch_bounds__(256) void prep(
    const float* __restrict__ X, const float* __restrict__ W,
    u16* __restrict__ Xb, u16* __restrict__ Wb,
    u16* __restrict__ Vf, float* __restrict__ SubP64)
{
  __shared__ u16 tr[64][65];
  __shared__ float cs[4][64];
  const int blk = blockIdx.x;
  const int tid = threadIdx.x;

  if (blk < 1024) {                       // ---- pack + convert-X + colsums ----
    const int kt = blk & 31, bh = blk >> 5;
    const int b = bh >> 4, h = bh & 15;
    const int w = tid >> 6, lane = tid & 63;
    {
      const int row = tid >> 2;            // 0..63
      const int c0  = (tid & 3) * 16;      // float col base
      const float* xp = X + ((size_t)b * T_ + kt * 64 + row) * C_ + h * 64 + c0;
      float vals[16];
#pragma unroll
      for (int q = 0; q < 4; ++q) {
        float4 v = *(const float4*)(xp + q * 4);
        vals[q * 4 + 0] = v.x; vals[q * 4 + 1] = v.y;
        vals[q * 4 + 2] = v.z; vals[q * 4 + 3] = v.w;
      }
      u16 xb[16];
#pragma unroll
      for (int i = 0; i < 16; ++i) xb[i] = f2bf(vals[i]);
      u16* xq = Xb + ((size_t)(b * T_ + kt * 64 + row)) * C_ + h * 64 + c0;
      *(bf16x8*)xq       = *(const bf16x8*)&xb[0];
      *(bf16x8*)(xq + 8) = *(const bf16x8*)&xb[8];
#pragma unroll
      for (int i = 0; i < 16; ++i) tr[row][c0 + i] = xb[i];
#pragma unroll
      for (int m = 4; m <= 32; m <<= 1)
#pragma unroll
        for (int i = 0; i < 16; ++i) vals[i] += __shfl_xor(vals[i], m);
      if (lane < 4) {
        float* dst = &cs[w][lane * 16];
#pragma unroll
        for (int q = 0; q < 4; ++q) {
          f32x4 s4 = { vals[q * 4 + 0], vals[q * 4 + 1], vals[q * 4 + 2], vals[q * 4 + 3] };
          *(f32x4*)&dst[q * 4] = s4;
        }
      }
    }
    __syncthreads();
    {
      const int quad = (lane >> 4), l16 = lane & 15;
      u16* outb = Vf + ((size_t)bh * 32 + kt) * 4096;
#pragma unroll
      for (int c = 0; c < 2; ++c) {
        u16 tmp[8];
#pragma unroll
        for (int j = 0; j < 8; ++j) tmp[j] = tr[c * 32 + quad * 8 + j][w * 16 + l16];
        *(bf16x8*)&outb[((w * 2 + c) * 64 + lane) * 8] = *(const bf16x8*)tmp;
      }
    }
    if (tid < 64)
      SubP64[(size_t)bh * 2048 + kt * 64 + tid] =
          cs[0][tid] + cs[1][tid] + cs[2][tid] + cs[3][tid];
  } else {                                // ---- convert W ----
    int i = (blk - 1024) * 256 + tid;
    float4 v = ((const float4*)W)[i];
    ushort4 u = { f2bf(v.x), f2bf(v.y), f2bf(v.z), f2bf(v.w) };
    ((ushort4*)Wb)[i] = u;
  }
}

// ---------------------------------------------------------------------------
// Kernel 1 (REVERTED to round-7 exactly — proven 138.4us config):
// qk = Xb @ Wb^T (M=4096,N=2048,K=1024), 128x128 tile, BK=64,
// global_load_lds width=16, __syncthreads double-buffer (tripwire-proven),
// T2 XOR-swizzle both sides. r9's 128x64 tile regressed (+7us: staging
// traffic 256->384MB); 128x128 is this structure's operating point.
// ---------------------------------------------------------------------------
__global__ __launch_bounds__(256) void gemm_qk(
    const u16* __restrict__ Xb, const u16* __restrict__ Wb,
    u16* __restrict__ Qo, u16* __restrict__ Kf)
{
  __shared__ __align__(16) u16 As[2][128 * 64];
  __shared__ __align__(16) u16 Bs[2][128 * 64];

  const int tid  = threadIdx.x;
  const int w    = tid >> 6;
  const int lane = tid & 63;
  const int quad = lane >> 4;
  const int l16  = lane & 15;
  const int m0 = blockIdx.y * 128;
  const int n0 = blockIdx.x * 128;

  const int grow = w * 8 + ((lane >> 3) & 7);
  // source-side swizzle: global chunk = (dest chunk) ^ (row&7)
  const int gcol = (((lane & 7) ^ ((lane >> 3) & 7)) * 8);

  f32x4 zero = {0.f, 0.f, 0.f, 0.f};
  f32x4 acc[4][4];
#pragma unroll
  for (int i = 0; i < 4; ++i)
#pragma unroll
    for (int j = 0; j < 4; ++j) acc[i][j] = zero;

  const int wr = (w >> 1) * 64, wc = (w & 1) * 64;

  const u16* gax = Xb + (size_t)(m0 + grow) * C_ + gcol;
  const u16* gbx = Wb + (size_t)(n0 + grow) * C_ + gcol;

#define GISSUE(K, BUF)                                                      \
  {                                                                         \
    _Pragma("unroll") for (int r = 0; r < 4; ++r) {                         \
      __builtin_amdgcn_global_load_lds(                                     \
          (const __attribute__((address_space(1))) void*)(gax + (size_t)r * 32 * C_ + (K)), \
          (__attribute__((address_space(3))) void*)&As[BUF][(w * 8 + r * 32) * 64], \
          16, 0, 0);                                                        \
      __builtin_amdgcn_global_load_lds(                                     \
          (const __attribute__((address_space(1))) void*)(gbx + (size_t)r * 32 * C_ + (K)), \
          (__attribute__((address_space(3))) void*)&Bs[BUF][(w * 8 + r * 32) * 64], \
          16, 0, 0);                                                        \
    }                                                                       \
  }

  GISSUE(0, 0);
#pragma unroll 2
  for (int it = 0; it < 16; ++it) {
    const int cur = it & 1;
    __syncthreads();                 // publishes buf[cur]; buf[cur^1] free
    if (it < 15) GISSUE((it + 1) * 64, cur ^ 1);
#pragma unroll
    for (int c = 0; c < 2; ++c) {
      bf16x8 af[4], bf[4];
#pragma unroll
      for (int i = 0; i < 4; ++i)
        af[i] = *(const bf16x8*)&As[cur][(wr + i * 16 + l16) * 64
                                         + (((c * 4 + quad) ^ (l16 & 7)) * 8)];
#pragma unroll
      for (int j = 0; j < 4; ++j)
        bf[j] = *(const bf16x8*)&Bs[cur][(wc + j * 16 + l16) * 64
                                         + (((c * 4 + quad) ^ (l16 & 7)) * 8)];
#pragma unroll
      for (int i = 0; i < 4; ++i)
#pragma unroll
        for (int j = 0; j < 4; ++j)
          acc[i][j] = __builtin_amdgcn_mfma_f32_16x16x32_bf16(af[i], bf[j], acc[i][j], 0, 0, 0);
    }
  }
#undef GISSUE

  // C/D layout: col = lane&15, row = quad*4 + reg (verified m89/m91)
#pragma unroll
  for (int i = 0; i < 4; ++i) {
    const int t_base = m0 + wr + i * 16;       // 16-aligned
    const int bidx = t_base >> 11;
    const int kt   = (t_base & 2047) >> 6;
    const int trow = (t_base & 2047) + quad * 4;
#pragma unroll
    for (int j = 0; j < 4; ++j) {
      const int n = n0 + wc + j * 16 + l16;    // wave-uniform branch base
      if (n < C_) {
        const int hq = n >> 6, d = n & 63;
        u16* qp = Qo + (((size_t)bidx * H_ + hq) * T_ + trow) * HD_ + d;
#pragma unroll
        for (int r = 0; r < 4; ++r) qp[(size_t)r * HD_] = f2bf(0.125f * acc[i][j][r]);
      } else {
        const int nh = n - C_;
        const int hh = nh >> 6, d = nh & 63;
        u16* kp = Kf + (((((size_t)(bidx * H_ + hh) * 32 + kt) * 4 + i) * 2 + (d >> 5)) * 64
                        + ((d >> 3) & 3) * 16 + quad * 4) * 8 + (d & 7);
#pragma unroll
        for (int r = 0; r < 4; ++r) kp[(size_t)r * 8] = f2bf(acc[i][j][r]);
      }
    }
  }
}

// ---------------------------------------------------------------------------
// Kernel 2 (ROUND-10): 128-q-row blocks (r3's proven geometry) + in-register
// P (r6's proven path). 512 blocks (32bh x 16jq), 8 waves x 16 q-rows; each
// K/V tile staged ONCE per 128 rows (traffic & barrier rounds halved vs the
// 64-row parity scheme), every wave computes every staged tile <= its own
// causal q-tile; no parity idle waves, no combine phase.
// Compute body identical to r6 (wq = w&3 within the wave's 64-tile,
// qt_w = 2jq + (w>>2)); epilogue = r3's verified 128-row code.
// LDS: loop 32KB (Ks/Vs dbuf); epilogue Xt[128][68]+G+GP = 38912B.
// ---------------------------------------------------------------------------
__global__ __launch_bounds__(512) void attn_kernel(
    const u16* __restrict__ Q, const u16* __restrict__ Kf, const u16* __restrict__ Vf,
    const float* __restrict__ SubP64, const float* __restrict__ X, float* __restrict__ out,
    const float* __restrict__ alphap, const float* __restrict__ betap,
    const float* __restrict__ gammap)
{
  __shared__ __align__(16) char smem[38912];
  u16 (*Ks)[4096] = (u16(*)[4096])(smem);            // [2][4096] u16 = 16KB
  u16 (*Vs)[4096] = (u16(*)[4096])(smem + 16384);    // [2][4096] u16 = 16KB

  const int tid  = threadIdx.x;
  const int w    = tid >> 6;          // 0..7
  const int wq   = w & 3;             // q-row group within the wave's 64-tile
  const int lane = tid & 63;
  const int quad = lane >> 4;
  const int l16  = lane & 15;
  const int jq = 15 - blockIdx.y;     // LPT: heavy q-superblocks first
  const int bh = blockIdx.x;
  const int b = bh >> 4, h = bh & 15;

  const int qt_w  = 2 * jq + (w >> 2);   // this wave's causal q-tile
  const int qtmax = 2 * jq + 1;          // tiles staged: kt = 0..qtmax

  const u16* kfb = Kf + (size_t)bh * T_ * HD_;
  const u16* vfb = Vf + (size_t)bh * T_ * HD_;

  bf16x8 qfrag[2];
  {
    const u16* qp = Q + ((size_t)bh * T_ + jq * 128 + w * 16 + l16) * HD_ + quad * 8;
    qfrag[0] = *(const bf16x8*)qp;
    qfrag[1] = *(const bf16x8*)(qp + 32);
  }

  bf16x8 onesf;
#pragma unroll
  for (int j = 0; j < 8; ++j) onesf[j] = (short)0x3F80;

  f32x4 zero = {0.f, 0.f, 0.f, 0.f};
  f32x4 acc[4] = {zero, zero, zero, zero};
  f32x4 accl = zero;

  // Stage one (K,V) tile pair: 16 chunks of 1KB; waves 0-3 -> K, 4-7 -> V,
  // 2 chunks each. LDS dst wave-uniform; src carries lane*16B.
#define STAGE(KT, BUF)                                                        \
  {                                                                           \
    const u16* sb = (w < 4) ? kfb : vfb;                                      \
    u16* db = (w < 4) ? &Ks[BUF][0] : &Vs[BUF][0];                            \
    const int ch = (w & 3) * 2;                                               \
    _Pragma("unroll") for (int ci = 0; ci < 2; ++ci) {                        \
      __builtin_amdgcn_global_load_lds(                                       \
          (const __attribute__((address_space(1))) void*)(                    \
              sb + (size_t)(KT) * 4096 + (ch + ci) * 512 + lane * 8),         \
          (__attribute__((address_space(3))) void*)(db + (ch + ci) * 512),    \
          16, 0, 0);                                                          \
    }                                                                         \
  }

  STAGE(0, 0);
  for (int kt = 0; kt <= qtmax; ++kt) {
    const int cur = kt & 1;
    __syncthreads();                 // publishes buf[cur]; buf[cur^1] free
    if (kt < qtmax) STAGE(kt + 1, cur ^ 1);
    if (kt <= qt_w) {
      const u16* Ksb = Ks[cur];
      const u16* Vsb = Vs[cur];
      const bool diag = (kt == qt_w);

      // swapped QK^T: lane(quad,l16) gets S^T[k = nb*16+quad*4+r][q = l16]
      f32x4 sfr[4] = {zero, zero, zero, zero};
#pragma unroll
      for (int cc = 0; cc < 2; ++cc)
#pragma unroll
        for (int nb = 0; nb < 4; ++nb) {
          bf16x8 kf = *(const bf16x8*)&Ksb[((nb * 2 + cc) * 64 + lane) * 8];
          sfr[nb] = __builtin_amdgcn_mfma_f32_16x16x32_bf16(kf, qfrag[cc], sfr[nb], 0, 0, 0);
        }

      // exp + causal mask + pack to bf16 pairs (k ascending within each u32)
      unsigned pkk[4][2];
#pragma unroll
      for (int nb = 0; nb < 4; ++nb) {
        float p[4];
#pragma unroll
        for (int r = 0; r < 4; ++r) {
          float e = __expf(sfr[nb][r]);
          if (diag && (nb * 16 + quad * 4 + r > wq * 16 + l16)) e = 0.f;
          p[r] = e;
        }
        asm("v_cvt_pk_bf16_f32 %0, %1, %2" : "=v"(pkk[nb][0]) : "v"(p[0]), "v"(p[1]));
        asm("v_cvt_pk_bf16_f32 %0, %1, %2" : "=v"(pkk[nb][1]) : "v"(p[2]), "v"(p[3]));
      }

      // redistribute to PV A-fragments via gfx950 builtins
#pragma unroll
      for (int g = 0; g < 2; ++g) {
        u32x2 s0 = __builtin_amdgcn_permlane32_swap(pkk[2 * g][0], pkk[2 * g + 1][0], false, false);
        u32x2 s1 = __builtin_amdgcn_permlane32_swap(pkk[2 * g][1], pkk[2 * g + 1][1], false, false);
        u32x2 t0 = __builtin_amdgcn_permlane16_swap(s0[0], s0[1], false, false);
        u32x2 t1 = __builtin_amdgcn_permlane16_swap(s1[0], s1[1], false, false);
        union { unsigned u[4]; bf16x8 v; } pa;
        pa.u[0] = t0[0]; pa.u[1] = t1[0]; pa.u[2] = t0[1]; pa.u[3] = t1[1];
        accl = __builtin_amdgcn_mfma_f32_16x16x32_bf16(pa.v, onesf, accl, 0, 0, 0);
#pragma unroll
        for (int nb = 0; nb < 4; ++nb) {
          bf16x8 vf = *(const bf16x8*)&Vsb[((nb * 2 + g) * 64 + lane) * 8];
          acc[nb] = __builtin_amdgcn_mfma_f32_16x16x32_bf16(pa.v, vf, acc[nb], 0, 0, 0);
        }
      }
    }
  }
#undef STAGE

  // ---------------- fused epilogue (128 rows, 512 threads; r3-verified) ----
  __syncthreads();                        // all waves done with Ks/Vs
  float* Xt = (float*)smem;               // [128][68] f32 = 34816
  float* G  = (float*)(smem + 34816);     // [8][64]
  float* GP = (float*)(smem + 36864);     // [8][64]

  {
    const int row = tid >> 2, c0 = (tid & 3) * 16;
    const float* xp = X + ((size_t)b * T_ + jq * 128 + row) * C_ + h * 64 + c0;
#pragma unroll
    for (int q = 0; q < 4; ++q) {
      float4 v = *(const float4*)(xp + q * 4);
      Xt[row * 68 + c0 + q * 4 + 0] = v.x;
      Xt[row * 68 + c0 + q * 4 + 1] = v.y;
      Xt[row * 68 + c0 + q * 4 + 2] = v.z;
      Xt[row * 68 + c0 + q * 4 + 3] = v.w;
    }
  }
  {
    float p = 0.f;
    for (int i = w; i < 2 * jq; i += 8)
      p += SubP64[(size_t)bh * 2048 + i * 64 + lane];
    GP[w * 64 + lane] = p;
  }
  __syncthreads();
  {
    float g = 0.f;
#pragma unroll
    for (int i = 0; i < 16; ++i) g += Xt[(w * 16 + i) * 68 + lane];
    G[w * 64 + lane] = g;
  }
  __syncthreads();
  {
    const float alpha = *alphap, gamma = *gammap;
    float run = 0.f;
#pragma unroll
    for (int k = 0; k < 8; ++k) run += GP[k * 64 + lane];
    for (int g = 0; g < w; ++g) run += G[g * 64 + lane];
    const int tbase = jq * 128 + w * 16;
#pragma unroll
    for (int i = 0; i < 16; ++i) {
      float v = Xt[(w * 16 + i) * 68 + lane];
      run += v;
      Xt[(w * 16 + i) * 68 + lane] =
          alpha * v - gamma * run * __builtin_amdgcn_rcpf((float)(tbase + i + 1));
    }
  }
  __syncthreads();

  {
    const float beta = *betap;
    float rl[4];
#pragma unroll
    for (int r = 0; r < 4; ++r) rl[r] = beta * __builtin_amdgcn_rcpf(accl[r]);
    const int myrow = w * 16 + quad * 4;   // row within 128-row block
#pragma unroll
    for (int nb = 0; nb < 4; ++nb) {
#pragma unroll
      for (int r = 0; r < 4; ++r) {
        int t = jq * 128 + myrow + r;
        int d = nb * 16 + l16;
        out[((size_t)b * T_ + t) * C_ + h * 64 + d] =
            Xt[(myrow + r) * 68 + d] + rl[r] * acc[nb][r];
      }
    }
  }
}

// ---------------------------------------------------------------------------
extern "C" void kernel_launch(void* const* d_in, const int* in_sizes, int n_in,
                              void* d_out, int out_size, void* d_ws, size_t ws_size,
                              hipStream_t stream) {
  const float* x      = (const float*)d_in[0];
  const float* W_attn = (const float*)d_in[1];
  const float* alphap = (const float*)d_in[2];
  const float* betap  = (const float*)d_in[3];
  const float* gammap = (const float*)d_in[4];
  float* out = (float*)d_out;

  // ws: Qb@0(8M) Kf@8(8M) Vf@16(8M) SubP64@24(.25M) Xb@25(8M) Wb@33(4M) = 37M
  char* ws = (char*)d_ws;
  u16*   Qb     = (u16*)(ws);
  u16*   Kfb    = (u16*)(ws + (8ull  << 20));
  u16*   Vfb    = (u16*)(ws + (16ull << 20));
  float* SubP64 = (float*)(ws + (24ull << 20));
  u16*   Xb     = (u16*)(ws + (25ull << 20));
  u16*   Wb     = (u16*)(ws + (33ull << 20));

  prep<<<3072, 256, 0, stream>>>(x, W_attn, Xb, Wb, Vfb, SubP64);
  gemm_qk<<<dim3(16, 32), 256, 0, stream>>>(Xb, Wb, Qb, Kfb);
  attn_kernel<<<dim3(32, 16), 512, 0, stream>>>(Qb, Kfb, Vfb, SubP64, x, out,
                                                alphap, betap, gammap);
}

// Round 11
// 131.536 us; speedup vs baseline: 1.1050x; 1.0925x over previous
//
#include <hip/hip_runtime.h>
#include <hip/hip_bf16.h>

typedef __attribute__((ext_vector_type(8))) short bf16x8;
typedef __attribute__((ext_vector_type(4))) float f32x4;
typedef __attribute__((ext_vector_type(2))) unsigned int u32x2;
typedef unsigned short u16;

#define B_  2
#define T_  2048
#define C_  1024
#define H_  16
#define HD_ 64

static __device__ __forceinline__ u16 f2bf(float f) {
  unsigned u = __float_as_uint(f);
  u += 0x7fffu + ((u >> 16) & 1u);   // round-to-nearest-even
  return (u16)(u >> 16);
}

// ---------------------------------------------------------------------------
// Kernel 0 "prep": two regions in one dispatch
//   [0,1024):   pack block (bh,kt): read 64x64 X tile fp32 once ->
//               Xb (bf16 row-major), Vf (MFMA-fragment layout), and
//               SubP64[bh][kt][d] = column sums (fp32, via xor-shuffles)
//   [1024,3072): convert W fp32->bf16 (float4 vectorized)
// ---------------------------------------------------------------------------
#define NW4 524288    // W float4 count
__global__ __launch_bounds__(256) void prep(
    const float* __restrict__ X, const float* __restrict__ W,
    u16* __restrict__ Xb, u16* __restrict__ Wb,
    u16* __restrict__ Vf, float* __restrict__ SubP64)
{
  __shared__ u16 tr[64][65];
  __shared__ float cs[4][64];
  const int blk = blockIdx.x;
  const int tid = threadIdx.x;

  if (blk < 1024) {                       // ---- pack + convert-X + colsums ----
    const int kt = blk & 31, bh = blk >> 5;
    const int b = bh >> 4, h = bh & 15;
    const int w = tid >> 6, lane = tid & 63;
    {
      const int row = tid >> 2;            // 0..63
      const int c0  = (tid & 3) * 16;      // float col base
      const float* xp = X + ((size_t)b * T_ + kt * 64 + row) * C_ + h * 64 + c0;
      float vals[16];
#pragma unroll
      for (int q = 0; q < 4; ++q) {
        float4 v = *(const float4*)(xp + q * 4);
        vals[q * 4 + 0] = v.x; vals[q * 4 + 1] = v.y;
        vals[q * 4 + 2] = v.z; vals[q * 4 + 3] = v.w;
      }
      u16 xb[16];
#pragma unroll
      for (int i = 0; i < 16; ++i) xb[i] = f2bf(vals[i]);
      u16* xq = Xb + ((size_t)(b * T_ + kt * 64 + row)) * C_ + h * 64 + c0;
      *(bf16x8*)xq       = *(const bf16x8*)&xb[0];
      *(bf16x8*)(xq + 8) = *(const bf16x8*)&xb[8];
#pragma unroll
      for (int i = 0; i < 16; ++i) tr[row][c0 + i] = xb[i];
#pragma unroll
      for (int m = 4; m <= 32; m <<= 1)
#pragma unroll
        for (int i = 0; i < 16; ++i) vals[i] += __shfl_xor(vals[i], m);
      if (lane < 4) {
        float* dst = &cs[w][lane * 16];
#pragma unroll
        for (int q = 0; q < 4; ++q) {
          f32x4 s4 = { vals[q * 4 + 0], vals[q * 4 + 1], vals[q * 4 + 2], vals[q * 4 + 3] };
          *(f32x4*)&dst[q * 4] = s4;
        }
      }
    }
    __syncthreads();
    {
      const int quad = (lane >> 4), l16 = lane & 15;
      u16* outb = Vf + ((size_t)bh * 32 + kt) * 4096;
#pragma unroll
      for (int c = 0; c < 2; ++c) {
        u16 tmp[8];
#pragma unroll
        for (int j = 0; j < 8; ++j) tmp[j] = tr[c * 32 + quad * 8 + j][w * 16 + l16];
        *(bf16x8*)&outb[((w * 2 + c) * 64 + lane) * 8] = *(const bf16x8*)tmp;
      }
    }
    if (tid < 64)
      SubP64[(size_t)bh * 2048 + kt * 64 + tid] =
          cs[0][tid] + cs[1][tid] + cs[2][tid] + cs[3][tid];
  } else {                                // ---- convert W ----
    int i = (blk - 1024) * 256 + tid;
    float4 v = ((const float4*)W)[i];
    ushort4 u = { f2bf(v.x), f2bf(v.y), f2bf(v.z), f2bf(v.w) };
    ((ushort4*)Wb)[i] = u;
  }
}

// ---------------------------------------------------------------------------
// Kernel 1 (ROUND-11): 128x128 tile, BK=64 — SAME tile/traffic/sync as the
// proven r7 config, but 8 WAVES x 512 threads (was 4x256): per-wave output
// 64x32 (acc 4x2, -32 VGPR), waves 0-3 stage A / 4-7 stage B (4 loads each).
// Grid 512 = 2 blocks/CU caps blocks; this doubles resident waves to 16/CU
// (4/SIMD) so sibling/other-block waves cover the barrier drain (m114
// wave-overlap). No sync-protocol change (__syncthreads dbuf, tripwire-
// proven); T2 XOR-swizzle both sides unchanged from r7.
// C-write algebra: wr=(w>>2)*64 stays multiple of 64 -> Kf frag index i
// derivation unchanged; wc=(w&3)*32, j in {0,1}.
// Q row-major [B,H,T,hd] PRE-SCALED by 0.125; K into fragment-linear Kf.
// ---------------------------------------------------------------------------
__global__ __launch_bounds__(512) void gemm_qk(
    const u16* __restrict__ Xb, const u16* __restrict__ Wb,
    u16* __restrict__ Qo, u16* __restrict__ Kf)
{
  __shared__ __align__(16) u16 As[2][128 * 64];
  __shared__ __align__(16) u16 Bs[2][128 * 64];

  const int tid  = threadIdx.x;
  const int w    = tid >> 6;          // 0..7
  const int w4   = w & 3;
  const int lane = tid & 63;
  const int quad = lane >> 4;
  const int l16  = lane & 15;
  const int m0 = blockIdx.y * 128;
  const int n0 = blockIdx.x * 128;

  const int grow = w4 * 8 + ((lane >> 3) & 7);
  // source-side swizzle: global chunk = (dest chunk) ^ (row&7)
  const int gcol = (((lane & 7) ^ ((lane >> 3) & 7)) * 8);

  f32x4 zero = {0.f, 0.f, 0.f, 0.f};
  f32x4 acc[4][2];
#pragma unroll
  for (int i = 0; i < 4; ++i)
#pragma unroll
    for (int j = 0; j < 2; ++j) acc[i][j] = zero;

  const int wr = (w >> 2) * 64;       // M half   (multiple of 64)
  const int wc = w4 * 32;             // N quarter

  const u16* gax = Xb + (size_t)(m0 + grow) * C_ + gcol;
  const u16* gbx = Wb + (size_t)(n0 + grow) * C_ + gcol;

#define GISSUE(K, BUF)                                                      \
  {                                                                         \
    if (w < 4) {                                                            \
      _Pragma("unroll") for (int r = 0; r < 4; ++r) {                       \
        __builtin_amdgcn_global_load_lds(                                   \
            (const __attribute__((address_space(1))) void*)(gax + (size_t)r * 32 * C_ + (K)), \
            (__attribute__((address_space(3))) void*)&As[BUF][(w4 * 8 + r * 32) * 64], \
            16, 0, 0);                                                      \
      }                                                                     \
    } else {                                                                \
      _Pragma("unroll") for (int r = 0; r < 4; ++r) {                       \
        __builtin_amdgcn_global_load_lds(                                   \
            (const __attribute__((address_space(1))) void*)(gbx + (size_t)r * 32 * C_ + (K)), \
            (__attribute__((address_space(3))) void*)&Bs[BUF][(w4 * 8 + r * 32) * 64], \
            16, 0, 0);                                                      \
      }                                                                     \
    }                                                                       \
  }

  GISSUE(0, 0);
#pragma unroll 2
  for (int it = 0; it < 16; ++it) {
    const int cur = it & 1;
    __syncthreads();                 // publishes buf[cur]; buf[cur^1] free
    if (it < 15) GISSUE((it + 1) * 64, cur ^ 1);
#pragma unroll
    for (int c = 0; c < 2; ++c) {
      bf16x8 af[4], bf[2];
#pragma unroll
      for (int i = 0; i < 4; ++i)
        af[i] = *(const bf16x8*)&As[cur][(wr + i * 16 + l16) * 64
                                         + (((c * 4 + quad) ^ (l16 & 7)) * 8)];
#pragma unroll
      for (int j = 0; j < 2; ++j)
        bf[j] = *(const bf16x8*)&Bs[cur][(wc + j * 16 + l16) * 64
                                         + (((c * 4 + quad) ^ (l16 & 7)) * 8)];
#pragma unroll
      for (int i = 0; i < 4; ++i)
#pragma unroll
        for (int j = 0; j < 2; ++j)
          acc[i][j] = __builtin_amdgcn_mfma_f32_16x16x32_bf16(af[i], bf[j], acc[i][j], 0, 0, 0);
    }
  }
#undef GISSUE

  // C/D layout: col = lane&15, row = quad*4 + reg (verified m89/m91)
#pragma unroll
  for (int i = 0; i < 4; ++i) {
    const int t_base = m0 + wr + i * 16;       // 16-aligned; wr multiple of 64
    const int bidx = t_base >> 11;
    const int kt   = (t_base & 2047) >> 6;
    const int trow = (t_base & 2047) + quad * 4;
#pragma unroll
    for (int j = 0; j < 2; ++j) {
      const int n = n0 + wc + j * 16 + l16;    // wave-uniform branch base
      if (n < C_) {
        const int hq = n >> 6, d = n & 63;
        u16* qp = Qo + (((size_t)bidx * H_ + hq) * T_ + trow) * HD_ + d;
#pragma unroll
        for (int r = 0; r < 4; ++r) qp[(size_t)r * HD_] = f2bf(0.125f * acc[i][j][r]);
      } else {
        const int nh = n - C_;
        const int hh = nh >> 6, d = nh & 63;
        u16* kp = Kf + (((((size_t)(bidx * H_ + hh) * 32 + kt) * 4 + i) * 2 + (d >> 5)) * 64
                        + ((d >> 3) & 3) * 16 + quad * 4) * 8 + (d & 7);
#pragma unroll
        for (int r = 0; r < 4; ++r) kp[(size_t)r * 8] = f2bf(acc[i][j][r]);
      }
    }
  }
}

// ---------------------------------------------------------------------------
// Kernel 2 (REVERTED to round-6 exactly — proven fastest attn, tripwire-
// clean; r10's 128-row variant regressed +5us from 2 blocks/CU + LPT tail):
// LDS-staged flash attention, P fully in-register via swapped QK^T +
// cvt_pk_bf16 + permlane32/16_swap builtins; parity split over kt across
// wave halves with additive LDS combine; fused epilogue.
// ---------------------------------------------------------------------------
__global__ __launch_bounds__(512) void attn_kernel(
    const u16* __restrict__ Q, const u16* __restrict__ Kf, const u16* __restrict__ Vf,
    const float* __restrict__ SubP64, const float* __restrict__ X, float* __restrict__ out,
    const float* __restrict__ alphap, const float* __restrict__ betap,
    const float* __restrict__ gammap)
{
  __shared__ __align__(16) char smem[32768];
  u16 (*Ks)[4096] = (u16(*)[4096])(smem);            // [2][4096] u16 = 16KB
  u16 (*Vs)[4096] = (u16(*)[4096])(smem + 16384);    // [2][4096] u16 = 16KB

  const int tid  = threadIdx.x;
  const int w    = tid >> 6;          // 0..7
  const int wq   = w & 3;             // q-row group (16 rows)
  const int parity = w >> 2;          // kt parity
  const int lane = tid & 63;
  const int quad = lane >> 4;
  const int l16  = lane & 15;
  const int qt = 31 - blockIdx.y;     // LPT: heavy q-tiles first
  const int bh = blockIdx.x;
  const int b = bh >> 4, h = bh & 15;

  const u16* kfb = Kf + (size_t)bh * T_ * HD_;
  const u16* vfb = Vf + (size_t)bh * T_ * HD_;

  bf16x8 qfrag[2];
  {
    const u16* qp = Q + ((size_t)bh * T_ + qt * 64 + wq * 16 + l16) * HD_ + quad * 8;
    qfrag[0] = *(const bf16x8*)qp;
    qfrag[1] = *(const bf16x8*)(qp + 32);
  }

  bf16x8 onesf;
#pragma unroll
  for (int j = 0; j < 8; ++j) onesf[j] = (short)0x3F80;

  f32x4 zero = {0.f, 0.f, 0.f, 0.f};
  f32x4 acc[4] = {zero, zero, zero, zero};
  f32x4 accl = zero;

  // Stage one (K,V) tile pair: 16 chunks of 1KB; waves 0-3 -> K, 4-7 -> V,
  // 2 chunks each. LDS dst wave-uniform; src carries lane*16B.
#define STAGE(KT, BUF)                                                        \
  {                                                                           \
    const u16* sb = (w < 4) ? kfb : vfb;                                      \
    u16* db = (w < 4) ? &Ks[BUF][0] : &Vs[BUF][0];                            \
    const int ch = (w & 3) * 2;                                               \
    _Pragma("unroll") for (int ci = 0; ci < 2; ++ci) {                        \
      __builtin_amdgcn_global_load_lds(                                       \
          (const __attribute__((address_space(1))) void*)(                    \
              sb + (size_t)(KT) * 4096 + (ch + ci) * 512 + lane * 8),         \
          (__attribute__((address_space(3))) void*)(db + (ch + ci) * 512),    \
          16, 0, 0);                                                          \
    }                                                                         \
  }

  STAGE(0, 0);
  for (int kt = 0; kt <= qt; ++kt) {
    const int cur = kt & 1;
    __syncthreads();                 // publishes buf[cur]; buf[cur^1] free
    if (kt < qt) STAGE(kt + 1, cur ^ 1);
    if (cur != parity) continue;     // wave-uniform
    const u16* Ksb = Ks[cur];
    const u16* Vsb = Vs[cur];
    const bool diag = (kt == qt);

    // swapped QK^T: lane(quad,l16) gets S^T[k = nb*16+quad*4+r][q = l16]
    f32x4 sfr[4] = {zero, zero, zero, zero};
#pragma unroll
    for (int cc = 0; cc < 2; ++cc)
#pragma unroll
      for (int nb = 0; nb < 4; ++nb) {
        bf16x8 kf = *(const bf16x8*)&Ksb[((nb * 2 + cc) * 64 + lane) * 8];
        sfr[nb] = __builtin_amdgcn_mfma_f32_16x16x32_bf16(kf, qfrag[cc], sfr[nb], 0, 0, 0);
      }

    // exp + causal mask + pack to bf16 pairs (k ascending within each u32)
    unsigned pkk[4][2];
#pragma unroll
    for (int nb = 0; nb < 4; ++nb) {
      float p[4];
#pragma unroll
      for (int r = 0; r < 4; ++r) {
        float e = __expf(sfr[nb][r]);
        if (diag && (nb * 16 + quad * 4 + r > wq * 16 + l16)) e = 0.f;
        p[r] = e;
      }
      asm("v_cvt_pk_bf16_f32 %0, %1, %2" : "=v"(pkk[nb][0]) : "v"(p[0]), "v"(p[1]));
      asm("v_cvt_pk_bf16_f32 %0, %1, %2" : "=v"(pkk[nb][1]) : "v"(p[2]), "v"(p[3]));
    }

    // redistribute to PV A-fragments via gfx950 builtins (returns
    // {new_vdst, new_vsrc}); routing element-verified:
    //   t[0] = A-frag u32 for even-source-quad pairs, t[1] = odd
#pragma unroll
    for (int g = 0; g < 2; ++g) {
      u32x2 s0 = __builtin_amdgcn_permlane32_swap(pkk[2 * g][0], pkk[2 * g + 1][0], false, false);
      u32x2 s1 = __builtin_amdgcn_permlane32_swap(pkk[2 * g][1], pkk[2 * g + 1][1], false, false);
      u32x2 t0 = __builtin_amdgcn_permlane16_swap(s0[0], s0[1], false, false);
      u32x2 t1 = __builtin_amdgcn_permlane16_swap(s1[0], s1[1], false, false);
      union { unsigned u[4]; bf16x8 v; } pa;
      pa.u[0] = t0[0]; pa.u[1] = t1[0]; pa.u[2] = t0[1]; pa.u[3] = t1[1];
      accl = __builtin_amdgcn_mfma_f32_16x16x32_bf16(pa.v, onesf, accl, 0, 0, 0);
#pragma unroll
      for (int nb = 0; nb < 4; ++nb) {
        bf16x8 vf = *(const bf16x8*)&Vsb[((nb * 2 + g) * 64 + lane) * 8];
        acc[nb] = __builtin_amdgcn_mfma_f32_16x16x32_bf16(pa.v, vf, acc[nb], 0, 0, 0);
      }
    }
  }
#undef STAGE

  // ---------------- combine odd-parity partials into waves 0-3 -------------
  __syncthreads();                        // all waves done with Ks/Vs
  {
    float* comb = (float*)smem;           // 256 x 20 f32 = 20480B
    if (parity == 1) {
      float* dst = comb + ((size_t)(wq * 64 + lane)) * 20;
#pragma unroll
      for (int nb = 0; nb < 4; ++nb) *(f32x4*)&dst[nb * 4] = acc[nb];
      *(f32x4*)&dst[16] = accl;
    }
    __syncthreads();
    if (parity == 0) {
      const float* src = comb + ((size_t)(wq * 64 + lane)) * 20;
#pragma unroll
      for (int nb = 0; nb < 4; ++nb) {
        f32x4 t = *(const f32x4*)&src[nb * 4];
        acc[nb] += t;
      }
      accl += *(const f32x4*)&src[16];
    }
  }
  __syncthreads();                        // comb region about to be reused

  // ---------------- fused epilogue (64 rows, 512 threads) ----------------
  float* Xt = (float*)smem;               // [64][68] f32 = 17408
  float* G  = (float*)(smem + 17408);     // [8][64]
  float* GP = (float*)(smem + 19456);     // [8][64]

  {
    const int row = tid >> 3, c0 = (tid & 7) * 8;
    const float* xp = X + ((size_t)b * T_ + qt * 64 + row) * C_ + h * 64 + c0;
#pragma unroll
    for (int q = 0; q < 2; ++q) {
      float4 v = *(const float4*)(xp + q * 4);
      Xt[row * 68 + c0 + q * 4 + 0] = v.x;
      Xt[row * 68 + c0 + q * 4 + 1] = v.y;
      Xt[row * 68 + c0 + q * 4 + 2] = v.z;
      Xt[row * 68 + c0 + q * 4 + 3] = v.w;
    }
  }
  {
    float p = 0.f;
    for (int i = w; i < qt; i += 8)
      p += SubP64[(size_t)bh * 2048 + i * 64 + lane];
    GP[w * 64 + lane] = p;
  }
  __syncthreads();
  {
    float g = 0.f;
#pragma unroll
    for (int i = 0; i < 8; ++i) g += Xt[(w * 8 + i) * 68 + lane];
    G[w * 64 + lane] = g;
  }
  __syncthreads();
  {
    const float alpha = *alphap, gamma = *gammap;
    float run = 0.f;
#pragma unroll
    for (int k = 0; k < 8; ++k) run += GP[k * 64 + lane];
    for (int g = 0; g < w; ++g) run += G[g * 64 + lane];
    const int tbase = qt * 64 + w * 8;
#pragma unroll
    for (int i = 0; i < 8; ++i) {
      float v = Xt[(w * 8 + i) * 68 + lane];
      run += v;
      Xt[(w * 8 + i) * 68 + lane] =
          alpha * v - gamma * run * __builtin_amdgcn_rcpf((float)(tbase + i + 1));
    }
  }
  __syncthreads();

  if (parity == 0) {
    const float beta = *betap;
    float rl[4];
#pragma unroll
    for (int r = 0; r < 4; ++r) rl[r] = beta * __builtin_amdgcn_rcpf(accl[r]);
    const int myrow = wq * 16 + quad * 4;
#pragma unroll
    for (int nb = 0; nb < 4; ++nb) {
#pragma unroll
      for (int r = 0; r < 4; ++r) {
        int t = qt * 64 + myrow + r;
        int d = nb * 16 + l16;
        out[((size_t)b * T_ + t) * C_ + h * 64 + d] =
            Xt[(myrow + r) * 68 + d] + rl[r] * acc[nb][r];
      }
    }
  }
}

// ---------------------------------------------------------------------------
extern "C" void kernel_launch(void* const* d_in, const int* in_sizes, int n_in,
                              void* d_out, int out_size, void* d_ws, size_t ws_size,
                              hipStream_t stream) {
  const float* x      = (const float*)d_in[0];
  const float* W_attn = (const float*)d_in[1];
  const float* alphap = (const float*)d_in[2];
  const float* betap  = (const float*)d_in[3];
  const float* gammap = (const float*)d_in[4];
  float* out = (float*)d_out;

  // ws: Qb@0(8M) Kf@8(8M) Vf@16(8M) SubP64@24(.25M) Xb@25(8M) Wb@33(4M) = 37M
  char* ws = (char*)d_ws;
  u16*   Qb     = (u16*)(ws);
  u16*   Kfb    = (u16*)(ws + (8ull  << 20));
  u16*   Vfb    = (u16*)(ws + (16ull << 20));
  float* SubP64 = (float*)(ws + (24ull << 20));
  u16*   Xb     = (u16*)(ws + (25ull << 20));
  u16*   Wb     = (u16*)(ws + (33ull << 20));

  prep<<<3072, 256, 0, stream>>>(x, W_attn, Xb, Wb, Vfb, SubP64);
  gemm_qk<<<dim3(16, 32), 512, 0, stream>>>(Xb, Wb, Qb, Kfb);
  attn_kernel<<<dim3(32, 32), 512, 0, stream>>>(Qb, Kfb, Vfb, SubP64, x, out,
                                                alphap, betap, gammap);
}